// Round 2
// baseline (642.199 us; speedup 1.0000x reference)
//
#include <hip/hip_runtime.h>
#include <hip/hip_bf16.h>

// out[r, n] = relu( sum_k concat[r,k] * W[k,n] ),
// concat = [review_row | user_row[perm_u] | item_row[perm_i]]
//
// R2 design: no LDS, no barrier. Each wave owns a 16-row x 64-col output
// tile. A-fragments are loaded straight from global (each source row is
// covered exactly once by its 4 quads -> no redundant fetch). B-fragments
// come from a 24 KB permuted bf16 W table (WT, built by prep_WT into d_ws)
// which is L1/L2-resident. W's rows are scatter-permuted once so the
// user/item gathers are plain contiguous row reads.

#define DIMS 64
#define K3 192

typedef float f32x4 __attribute__((ext_vector_type(4)));
typedef short s16x8 __attribute__((ext_vector_type(8)));
typedef __bf16 bf16x8 __attribute__((ext_vector_type(8)));

__device__ __forceinline__ short f2bf(float f) {
    union { float f; unsigned int u; } v; v.f = f;
    unsigned int u = v.u;
    u += 0x7fffu + ((u >> 16) & 1u);   // round-to-nearest-even
    return (short)(u >> 16);
}

__device__ __forceinline__ bf16x8 pack8(f32x4 x, f32x4 y) {
    s16x8 r;
    r[0] = f2bf(x[0]); r[1] = f2bf(x[1]); r[2] = f2bf(x[2]); r[3] = f2bf(x[3]);
    r[4] = f2bf(y[0]); r[5] = f2bf(y[1]); r[6] = f2bf(y[2]); r[7] = f2bf(y[3]);
    return __builtin_bit_cast(bf16x8, r);
}

// Prep: WT[n*192 + dk] = bf16(W[k*64+n]), dk = permuted destination k.
// 12288 elements, one per thread, 48 blocks.
__global__ void prep_WT(const float* __restrict__ W,
                        const int* __restrict__ perm_u,
                        const int* __restrict__ perm_i,
                        short* __restrict__ WT) {
    const int e = blockIdx.x * 256 + threadIdx.x;   // 0..12287
    const int k = e >> 6;                           // 0..191
    const int n = e & 63;
    const float w = W[e];
    int dk;
    if (k < 64)       dk = k;
    else if (k < 128) dk = 64 + perm_u[k - 64];
    else              dk = 128 + perm_i[k - 128];
    WT[n * K3 + dk] = f2bf(w);
}

__global__ __launch_bounds__(256, 6) void concat_agg_kernel(
        const float* __restrict__ review,
        const float* __restrict__ user,
        const float* __restrict__ item,
        const int* __restrict__ uadj,
        const int* __restrict__ iadj,
        const short* __restrict__ WT,    // bf16 bits, [64][192]
        float* __restrict__ out,
        int n_reviews) {
    const int t    = threadIdx.x;
    const int lane = t & 63;
    const int wv   = t >> 6;                 // 0..3
    const int m    = lane & 15;
    const int q    = lane >> 4;              // 0..3

    const int tile = blockIdx.x * 4 + wv;    // 16-row tile id
    int row = tile * 16 + m;
    if (row >= n_reviews) row = n_reviews - 1;

    const int u  = uadj[row];
    const int it = iadj[row];

    const float* pr = review + (size_t)row * DIMS + q * 8;
    const float* pu = user   + (size_t)u   * DIMS + q * 8;
    const float* pi = item   + (size_t)it  * DIMS + q * 8;

    // A fragments: ks 0..5 cover [review | user | item], cols q*8 and 32+q*8.
    f32x4 af0 = __builtin_nontemporal_load((const f32x4*)pr);
    f32x4 af1 = __builtin_nontemporal_load((const f32x4*)pr + 1);
    f32x4 af2 = __builtin_nontemporal_load((const f32x4*)(pr + 32));
    f32x4 af3 = __builtin_nontemporal_load((const f32x4*)(pr + 32) + 1);
    f32x4 af4 = ((const f32x4*)pu)[0];
    f32x4 af5 = ((const f32x4*)pu)[1];
    f32x4 af6 = ((const f32x4*)(pu + 32))[0];
    f32x4 af7 = ((const f32x4*)(pu + 32))[1];
    f32x4 af8 = ((const f32x4*)pi)[0];
    f32x4 af9 = ((const f32x4*)pi)[1];
    f32x4 afa = ((const f32x4*)(pi + 32))[0];
    f32x4 afb = ((const f32x4*)(pi + 32))[1];

    bf16x8 a[6];
    a[0] = pack8(af0, af1);
    a[1] = pack8(af2, af3);
    a[2] = pack8(af4, af5);
    a[3] = pack8(af6, af7);
    a[4] = pack8(af8, af9);
    a[5] = pack8(afa, afb);

    // B fragments from L1-resident WT: row n = nt*16 + m, cols ks*32 + q*8.
    const short* wbase = WT + m * K3 + q * 8;

    f32x4 acc0 = {0.f,0.f,0.f,0.f}, acc1 = {0.f,0.f,0.f,0.f};
    f32x4 acc2 = {0.f,0.f,0.f,0.f}, acc3 = {0.f,0.f,0.f,0.f};

    #pragma unroll
    for (int ks = 0; ks < 6; ++ks) {
        bf16x8 b0 = __builtin_bit_cast(bf16x8, *(const s16x8*)(wbase + 0 * 16 * K3 + ks * 32));
        bf16x8 b1 = __builtin_bit_cast(bf16x8, *(const s16x8*)(wbase + 1 * 16 * K3 + ks * 32));
        bf16x8 b2 = __builtin_bit_cast(bf16x8, *(const s16x8*)(wbase + 2 * 16 * K3 + ks * 32));
        bf16x8 b3 = __builtin_bit_cast(bf16x8, *(const s16x8*)(wbase + 3 * 16 * K3 + ks * 32));
        acc0 = __builtin_amdgcn_mfma_f32_16x16x32_bf16(a[ks], b0, acc0, 0, 0, 0);
        acc1 = __builtin_amdgcn_mfma_f32_16x16x32_bf16(a[ks], b1, acc1, 0, 0, 0);
        acc2 = __builtin_amdgcn_mfma_f32_16x16x32_bf16(a[ks], b2, acc2, 0, 0, 0);
        acc3 = __builtin_amdgcn_mfma_f32_16x16x32_bf16(a[ks], b3, acc3, 0, 0, 0);
    }

    // Epilogue: C/D layout col = lane&15 (= m), row = q*4 + reg.
    const int rbase = tile * 16 + q * 4;
    #pragma unroll
    for (int v = 0; v < 4; ++v) {
        const int rr = rbase + v;
        if (rr < n_reviews) {
            float* orow = out + (size_t)rr * DIMS + m;
            __builtin_nontemporal_store(fmaxf(acc0[v], 0.0f), orow +  0);
            __builtin_nontemporal_store(fmaxf(acc1[v], 0.0f), orow + 16);
            __builtin_nontemporal_store(fmaxf(acc2[v], 0.0f), orow + 32);
            __builtin_nontemporal_store(fmaxf(acc3[v], 0.0f), orow + 48);
        }
    }
}

extern "C" void kernel_launch(void* const* d_in, const int* in_sizes, int n_in,
                              void* d_out, int out_size, void* d_ws, size_t ws_size,
                              hipStream_t stream) {
    (void)n_in; (void)out_size; (void)ws_size;
    const float* review = (const float*)d_in[0];
    const float* user   = (const float*)d_in[1];
    const float* item   = (const float*)d_in[2];
    const float* W      = (const float*)d_in[3];
    const int* uadj     = (const int*)d_in[4];
    const int* iadj     = (const int*)d_in[5];
    const int* perm_u   = (const int*)d_in[6];
    const int* perm_i   = (const int*)d_in[7];
    float* out = (float*)d_out;
    short* WT = (short*)d_ws;  // 12288 bf16 = 24 KB scratch

    const int n_reviews = in_sizes[0] / DIMS;

    prep_WT<<<48, 256, 0, stream>>>(W, perm_u, perm_i, WT);

    const int grid = (n_reviews + 63) / 64;   // 4 waves/block, 16 rows/wave
    concat_agg_kernel<<<grid, 256, 0, stream>>>(review, user, item, uadj, iadj,
                                                WT, out, n_reviews);
}